// Round 2
// baseline (158.675 us; speedup 1.0000x reference)
//
#include <hip/hip_runtime.h>
#include <math.h>

// Problem constants (from reference)
#define Bdim 32
#define Ndim 325
#define Kdim 20
#define Sdim 12      // S_IN == S_OUT == 12
#define Cdim 10
#define Hdim 48      // 4*S_OUT
#define NB   (Bdim*Ndim)                  // 10400 (b,n) pairs
#define OUT_SCALARS (NB*Cdim*Sdim)        // output_data floats, then 3 scalars
#define BN_BLOCKS (NB/4)                  // 2600 blocks (4 bn each)
#define NODE_BLOCKS 260                   // 40 nodes per block
#define NPB 40

// Workspace layout (float offsets); all blocks 16B-aligned. Layout kept
// identical to the verified version (partial slots now mostly unused).
#define O_WH  0                           // NB*12 node features wh
#define O_HX  (O_WH + NB*Sdim)            // NB*48: hx + a1_b (bias pre-folded)
#define O_HY  (O_HX + NB*Hdim)            // NB*48: hy
#define O_PCL (O_HY + NB*Hdim)
#define O_PDS (O_PCL + BN_BLOCKS)
#define O_PWH (O_PDS + BN_BLOCKS)         // NODE_BLOCKS wh-sum partials
#define WS_BASE_FLOATS (O_PWH + NODE_BLOCKS)

__device__ __forceinline__ float leaky(float x) { return x >= 0.f ? x : 0.5f * x; }

// ---------------------------------------------------------------------------
// K1: node kernel (verified 256-thread layout). 260 blocks; 40 nodes each.
// wh -> LDS + ws; hx(+b1), hy -> ws; per-BLOCK wh-sum partial.
// Block 0 additionally zeroes the 3 out scalars (K2 accumulates via atomics;
// kernel-boundary ordering guarantees visibility).
// ---------------------------------------------------------------------------
__global__ __launch_bounds__(256)
void node_kernel(const float* __restrict__ x,
                 const float* __restrict__ wW, const float* __restrict__ wb,
                 const float* __restrict__ A1, const float* __restrict__ b1,
                 float* __restrict__ ws, float* __restrict__ out)
{
    __shared__ float s_wh[NPB][Sdim];
    __shared__ float s_r[4];
    const int tid = threadIdx.x;
    const int base = blockIdx.x * NPB;

    if (blockIdx.x == 0 && tid < 3) out[OUT_SCALARS + tid] = 0.f;

    float v = 0.f;  // wh partial
    // wh: 40*12 = 480 elems
    #pragma unroll
    for (int rep = 0; rep < 2; rep++) {
        const int e = tid + rep * 256;
        if (e < NPB * Sdim) {
            const int n = e / Sdim, s = e - n * Sdim;
            const float* xr = x + (size_t)(base + n) * Sdim;
            float acc = wb[s];
            #pragma unroll
            for (int i = 0; i < Sdim; i++) acc += xr[i] * wW[i * Sdim + s];
            acc = leaky(acc);
            s_wh[n][s] = acc;
            ws[O_WH + (size_t)(base + n) * Sdim + s] = acc;
            v += acc;
        }
    }
    __syncthreads();

    // hx/hy: 40*96 = 3840 elems
    #pragma unroll
    for (int rep = 0; rep < 15; rep++) {
        const int e = tid + rep * 256;
        const int n = e / 96, r = e - n * 96;
        const int which = r / Hdim, d = r - which * Hdim;
        const float4 w0 = *(const float4*)&s_wh[n][0];
        const float4 w1 = *(const float4*)&s_wh[n][4];
        const float4 w2 = *(const float4*)&s_wh[n][8];
        const float* Ac = A1 + (which * Sdim) * Hdim + d;  // stride Hdim over s
        float acc = which ? 0.f : b1[d];                   // fold a1_b into hx
        acc += w0.x*Ac[0*Hdim] + w0.y*Ac[1*Hdim] + w0.z*Ac[2*Hdim] + w0.w*Ac[3*Hdim]
             + w1.x*Ac[4*Hdim] + w1.y*Ac[5*Hdim] + w1.z*Ac[6*Hdim] + w1.w*Ac[7*Hdim]
             + w2.x*Ac[8*Hdim] + w2.y*Ac[9*Hdim] + w2.z*Ac[10*Hdim] + w2.w*Ac[11*Hdim];
        ws[(which ? O_HY : O_HX) + (size_t)(base + n) * Hdim + d] = acc;
    }

    // block-reduce wh partial
    #pragma unroll
    for (int off = 32; off > 0; off >>= 1) v += __shfl_down(v, off);
    if ((tid & 63) == 0) s_r[tid >> 6] = v;
    __syncthreads();
    if (tid == 0) ws[O_PWH + blockIdx.x] = s_r[0] + s_r[1] + s_r[2] + s_r[3];
}

__device__ __forceinline__ float dot12(const float4& a0, const float4& a1, const float4& a2,
                                       const float4& b0, const float4& b1, const float4& b2)
{
    return a0.x*b0.x + a0.y*b0.y + a0.z*b0.z + a0.w*b0.w
         + a1.x*b1.x + a1.y*b1.y + a1.z*b1.z + a1.w*b1.w
         + a2.x*b2.x + a2.y*b2.y + a2.z*b2.z + a2.w*b2.w;
}

// ---------------------------------------------------------------------------
// K2 (merged att+bn+finalize): 4 bn per 256-thread block.
// Phase 0: stage A2 (padded rows, stride 12) + the block's 80 topk indices.
// Phase 1: lanes 0..159 = 2 lanes per edge: logits via LDS A2 wide reads,
//          shfl_xor combine, softmax -> s_am. Lanes 160..255 gather whj.
// Phase 2: per-slot norm (t<20) + einsum (20<=t<50); __syncthreads;
//          loss over 2x2 ROW-TILES spread across ALL 256 lanes (cross-slot):
//          220 tile-tasks, 4 rows (24 LDS b128) per 4 pairs instead of
//          12 b128/pair -> ~40% fewer loss LDS issue cycles.
// Tail: block partials pre-scaled -> atomicAdd to out scalars (K3 removed);
//       block 0 reduces K1's 260 wh partials.
// ---------------------------------------------------------------------------
__global__ __launch_bounds__(256)
void mega_kernel(const int* __restrict__ topk,
                 const float* __restrict__ A2, const float* __restrict__ b2,
                 float* __restrict__ ws, float* __restrict__ out)
{
    __shared__ float s_A2  [Hdim * 12];     // 48 rows, stride 12 (pad 2)
    __shared__ int   s_topk[80];
    __shared__ float s_whj [4][Kdim][12];   // 48B rows, float4-aligned, rows contiguous
    __shared__ float s_am  [4][Kdim][12];   // probs, c padded with zeros
    __shared__ float s_invn[4][Kdim];
    __shared__ float s_red[2][4];

    const int tid = threadIdx.x;
    const int slot = tid >> 6, t = tid & 63;

    // ---- phase 0: stage A2 (padded) and topk ----
    if (tid < 120) {
        const int e0 = tid * 4;   // 4 consecutive source floats
        #pragma unroll
        for (int u = 0; u < 4; u++) {
            const int e = e0 + u;
            const int d = e / Cdim, c = e - d * Cdim;
            s_A2[d * 12 + c] = A2[e];
        }
    } else if (tid < 200) {
        s_topk[tid - 120] = topk[blockIdx.x * 80 + (tid - 120)];
    }
    __syncthreads();

    if (tid < 160) {
        // ---- edge pair lanes: e = tid>>1, half = tid&1, 24 d's each ----
        const int e = tid >> 1, half = tid & 1;
        const int gid = blockIdx.x * 80 + e;
        const int bn_e = gid / Kdim;
        const int b_e  = bn_e / Ndim;
        const int j    = s_topk[e];
        const int ek   = e / 20, kk = e - ek * 20;   // (slot, k) of this edge

        const float4* hx4 = (const float4*)(ws + O_HX + (size_t)bn_e * Hdim) + half * 6;
        const float4* hy4 = (const float4*)(ws + O_HY + ((size_t)b_e * Ndim + j) * Hdim) + half * 6;

        float acc[Cdim];
        #pragma unroll
        for (int c = 0; c < Cdim; c++) acc[c] = 0.f;
        #pragma unroll
        for (int q = 0; q < 6; q++) {
            const float4 xv = hx4[q], yv = hy4[q];
            const float hh[4] = { leaky(xv.x + yv.x), leaky(xv.y + yv.y),
                                  leaky(xv.z + yv.z), leaky(xv.w + yv.w) };
            #pragma unroll
            for (int i = 0; i < 4; i++) {
                const int d = half * 24 + q * 4 + i;
                const float* Ar = &s_A2[d * 12];
                const float4 r0 = *(const float4*)(Ar + 0);
                const float4 r1 = *(const float4*)(Ar + 4);
                const float2 r2 = *(const float2*)(Ar + 8);
                const float h = hh[i];
                acc[0] += h * r0.x; acc[1] += h * r0.y;
                acc[2] += h * r0.z; acc[3] += h * r0.w;
                acc[4] += h * r1.x; acc[5] += h * r1.y;
                acc[6] += h * r1.z; acc[7] += h * r1.w;
                acc[8] += h * r2.x; acc[9] += h * r2.y;
            }
        }
        float full[Cdim];
        #pragma unroll
        for (int c = 0; c < Cdim; c++) full[c] = acc[c] + __shfl_xor(acc[c], 1);
        if (half == 0) {
            float m = -1e30f;
            #pragma unroll
            for (int c = 0; c < Cdim; c++) { full[c] = leaky(full[c] + b2[c]); m = fmaxf(m, full[c]); }
            float sum = 0.f;
            #pragma unroll
            for (int c = 0; c < Cdim; c++) { full[c] = __expf(full[c] - m); sum += full[c]; }
            const float inv = 1.f / sum;
            *(float4*)&s_am[ek][kk][0] = make_float4(full[0]*inv, full[1]*inv, full[2]*inv, full[3]*inv);
            *(float4*)&s_am[ek][kk][4] = make_float4(full[4]*inv, full[5]*inv, full[6]*inv, full[7]*inv);
            *(float4*)&s_am[ek][kk][8] = make_float4(full[8]*inv, full[9]*inv, 0.f, 0.f);
        }
    } else {
        // ---- gather lanes (96): 240 float4s of whj ----
        for (int i = tid - 160; i < 240; i += 96) {
            const int kf = i / 3, q = i - kf * 3;          // kf in [0,80)
            const int sl = kf / 20, k = kf - sl * 20;
            const int bn_i = (blockIdx.x * 80 + kf) / Kdim;
            const int b_i  = bn_i / Ndim;
            const int j    = s_topk[kf];
            const float4 v = *(const float4*)(ws + O_WH + ((size_t)b_i * Ndim + j) * Sdim + q * 4);
            *(float4*)&s_whj[sl][k][q * 4] = v;
        }
    }
    __syncthreads();

    const int bn = blockIdx.x * 4 + slot;
    float cl = 0.f, ds = 0.f;

    if (t < Kdim) {
        // per-k norm factor + diagonal dist contribution
        const float4 w0 = *(const float4*)&s_whj[slot][t][0];
        const float4 w1 = *(const float4*)&s_whj[slot][t][4];
        const float4 w2 = *(const float4*)&s_whj[slot][t][8];
        const float nn = dot12(w0, w1, w2, w0, w1, w2);
        const float invn = 1.f / (sqrtf(nn) + 1e-8f);
        s_invn[slot][t] = invn;
        ds += nn * invn * invn;               // dist_mat diagonal term
    } else if (t < Kdim + 30) {
        // output einsum: lane = (c, s-quad), float4 stores
        const int e = t - Kdim, c = e / 3, sq = e - c * 3;
        float4 o = make_float4(0.f, 0.f, 0.f, 0.f);
        #pragma unroll
        for (int k = 0; k < Kdim; k++) {
            const float a = s_am[slot][k][c];
            const float4 w = *(const float4*)&s_whj[slot][k][sq * 4];
            o.x += a * w.x; o.y += a * w.y; o.z += a * w.z; o.w += a * w.w;
        }
        *(float4*)(out + (size_t)bn * (Cdim * Sdim) + c * Sdim + sq * 4) = o;
    }
    __syncthreads();   // s_invn (cross-slot) must be visible to loss lanes

    // ---- loss: 2x2 row-tiles, 55 tiles/slot * 4 slots = 220 tasks ----
    // Tile (gi,gj), gi<=gj over 10 row-groups of 2. Off-diag tile: 4 pairs
    // (weight 2 each, symmetric). Diag tile: 1 pair (i0,j1), weight 2.
    // Diagonal dist entries handled by norm lanes above.
    if (tid < 220) {
        const int slot_l = tid / 55;
        const int t55 = tid - slot_l * 55;
        const int gi = (int)((21.0f - sqrtf((float)(441 - 8 * t55))) * 0.5f);
        const int gj = gi + (t55 - (gi * (21 - gi)) / 2);
        const int i0 = 2 * gi, j0 = 2 * gj;
        const bool diag = (gi == gj);

        const float4* W = (const float4*)&s_whj[slot_l][0][0];
        const float4* P = (const float4*)&s_am [slot_l][0][0];

        float4 wi[2][3], wj[2][3], pi[2][3], pj[2][3];
        #pragma unroll
        for (int u = 0; u < 2; u++) {
            #pragma unroll
            for (int q = 0; q < 3; q++) {
                wi[u][q] = W[(i0 + u) * 3 + q];
                wj[u][q] = W[(j0 + u) * 3 + q];
                pi[u][q] = P[(i0 + u) * 3 + q];
                pj[u][q] = P[(j0 + u) * 3 + q];
            }
        }
        const float inv_i0 = s_invn[slot_l][i0], inv_i1 = s_invn[slot_l][i0 + 1];
        const float inv_j0 = s_invn[slot_l][j0], inv_j1 = s_invn[slot_l][j0 + 1];
        const float inv_i[2] = { inv_i0, inv_i1 };
        const float inv_j[2] = { inv_j0, inv_j1 };

        #pragma unroll
        for (int ii = 0; ii < 2; ii++) {
            #pragma unroll
            for (int jj = 0; jj < 2; jj++) {
                const float wgt = diag ? ((ii == 0 && jj == 1) ? 2.f : 0.f) : 2.f;
                const float draw = dot12(wi[ii][0], wi[ii][1], wi[ii][2],
                                         wj[jj][0], wj[jj][1], wj[jj][2]);
                const float d = draw * inv_i[ii] * inv_j[jj];
                float p = dot12(pi[ii][0], pi[ii][1], pi[ii][2],
                                pj[jj][0], pj[jj][1], pj[jj][2]);   // pads are 0
                p = fminf(fmaxf(p, 1e-4f), 1.f - 1e-4f);
                const float lp = __logf(p);
                ds += wgt * d;
                cl += wgt * ((d >= 0.5f) ? -lp : lp);
            }
        }
    }

    // block-wide reduce (pairs were distributed cross-slot; only the block
    // total matters) -> pre-scaled atomicAdd into out scalars
    #pragma unroll
    for (int off = 32; off > 0; off >>= 1) {
        cl += __shfl_down(cl, off);
        ds += __shfl_down(ds, off);
    }
    if (t == 0) { s_red[0][slot] = cl; s_red[1][slot] = ds; }
    __syncthreads();
    if (tid == 0) {
        const float c = s_red[0][0] + s_red[0][1] + s_red[0][2] + s_red[0][3];
        const float d = s_red[1][0] + s_red[1][1] + s_red[1][2] + s_red[1][3];
        atomicAdd(&out[OUT_SCALARS + 0], c * (1.f / (float)NB));
        atomicAdd(&out[OUT_SCALARS + 1], d * (1.f / ((float)NB * Kdim * Kdim)));
    }

    // block 0: fold K1's wh partials into the mean scalar
    if (blockIdx.x == 0 && tid < 64) {
        float wm = 0.f;
        for (int i = tid; i < NODE_BLOCKS; i += 64) wm += ws[O_PWH + i];
        #pragma unroll
        for (int off = 32; off > 0; off >>= 1) wm += __shfl_down(wm, off);
        if (tid == 0) atomicAdd(&out[OUT_SCALARS + 2], wm * (1.f / ((float)NB * Sdim)));
    }
}

// ---------------------------------------------------------------------------
// Fallback: round-1 monolithic kernel (used only if ws is too small)
// ---------------------------------------------------------------------------
__global__ void zero_scalars(float* out) {
    const int t = threadIdx.x;
    if (t < 3) out[OUT_SCALARS + t] = 0.f;
}

__global__ __launch_bounds__(64)
void fused_kernel(const float* __restrict__ input_data,
                  const float* __restrict__ w_W,  const float* __restrict__ w_b,
                  const float* __restrict__ a1_W, const float* __restrict__ a1_b,
                  const float* __restrict__ a2_W, const float* __restrict__ a2_b,
                  const int*   __restrict__ topk,
                  float* __restrict__ out)
{
    __shared__ float s_wW[Sdim * Sdim];
    __shared__ float s_wb[Sdim];
    __shared__ float s_A1[2 * Sdim * Hdim];
    __shared__ float s_b1[Hdim];
    __shared__ float s_A2f[Hdim * Cdim];
    __shared__ float s_b2f[Cdim];
    __shared__ float s_whs[Sdim];
    __shared__ float s_hx[Hdim];
    __shared__ float s_whj[Kdim][Sdim + 1];
    __shared__ float s_hid[Kdim][Hdim + 1];
    __shared__ float s_am [Kdim][Cdim + 1];
    __shared__ float s_wtn[Kdim][Sdim + 1];
    __shared__ int   s_idx[Kdim];

    const int t = threadIdx.x, bn = blockIdx.x, b = bn / Ndim;

    for (int i = t; i < Sdim * Sdim; i += 64)      s_wW[i] = w_W[i];
    if (t < Sdim)                                  s_wb[t] = w_b[t];
    for (int i = t; i < 2 * Sdim * Hdim; i += 64)  s_A1[i] = a1_W[i];
    if (t < Hdim)                                  s_b1[t] = a1_b[t];
    for (int i = t; i < Hdim * Cdim; i += 64)      s_A2f[i] = a2_W[i];
    if (t < Cdim)                                  s_b2f[t] = a2_b[t];
    if (t < Kdim)                                  s_idx[t] = topk[(size_t)bn * Kdim + t];
    __syncthreads();

    const float* xs = input_data + (size_t)bn * Sdim;
    if (t < Sdim) {
        float acc = s_wb[t];
        #pragma unroll
        for (int i = 0; i < Sdim; i++) acc += xs[i] * s_wW[i * Sdim + t];
        s_whs[t] = leaky(acc);
    }
    __syncthreads();

    if (t < Hdim) {
        float acc = 0.f;
        #pragma unroll
        for (int s = 0; s < Sdim; s++) acc += s_whs[s] * s_A1[s * Hdim + t];
        s_hx[t] = acc;
    }
    for (int e = t; e < Kdim * Sdim; e += 64) {
        const int k = e / Sdim, ss = e - k * Sdim;
        const float* xj = input_data + ((size_t)b * Ndim + s_idx[k]) * Sdim;
        float acc = s_wb[ss];
        #pragma unroll
        for (int i = 0; i < Sdim; i++) acc += xj[i] * s_wW[i * Sdim + ss];
        s_whj[k][ss] = leaky(acc);
    }
    __syncthreads();

    for (int e = t; e < Kdim * Hdim; e += 64) {
        const int k = e / Hdim, d = e - k * Hdim;
        float acc = s_hx[d] + s_b1[d];
        #pragma unroll
        for (int s = 0; s < Sdim; s++) acc += s_whj[k][s] * s_A1[(Sdim + s) * Hdim + d];
        s_hid[k][d] = leaky(acc);
    }
    __syncthreads();

    for (int e = t; e < Kdim * Cdim; e += 64) {
        const int k = e / Cdim, c = e - k * Cdim;
        float acc = s_b2f[c];
        #pragma unroll
        for (int d = 0; d < Hdim; d++) acc += s_hid[k][d] * s_A2f[d * Cdim + c];
        s_am[k][c] = leaky(acc);
    }
    __syncthreads();

    if (t < Kdim) {
        float m = -1e30f;
        #pragma unroll
        for (int c = 0; c < Cdim; c++) m = fmaxf(m, s_am[t][c]);
        float ex[Cdim]; float sum = 0.f;
        #pragma unroll
        for (int c = 0; c < Cdim; c++) { ex[c] = expf(s_am[t][c] - m); sum += ex[c]; }
        const float inv = 1.f / sum;
        #pragma unroll
        for (int c = 0; c < Cdim; c++) s_am[t][c] = ex[c] * inv;
        float nn = 0.f;
        #pragma unroll
        for (int s = 0; s < Sdim; s++) nn += s_whj[t][s] * s_whj[t][s];
        const float invn = 1.f / (sqrtf(nn) + 1e-8f);
        #pragma unroll
        for (int s = 0; s < Sdim; s++) s_wtn[t][s] = s_whj[t][s] * invn;
    }
    __syncthreads();

    float* op = out + (size_t)bn * (Cdim * Sdim);
    for (int e = t; e < Cdim * Sdim; e += 64) {
        const int c = e / Sdim, ss = e - c * Sdim;
        float acc = 0.f;
        #pragma unroll
        for (int k = 0; k < Kdim; k++) acc += s_am[k][c] * s_whj[k][ss];
        op[e] = acc;
    }

    float cl = 0.f, ds = 0.f;
    for (int e = t; e < Kdim * Kdim; e += 64) {
        const int k = e / Kdim, l = e - k * Kdim;
        float d = 0.f;
        #pragma unroll
        for (int s = 0; s < Sdim; s++) d += s_wtn[k][s] * s_wtn[l][s];
        ds += d;
        if (k != l) {
            float p = 0.f;
            #pragma unroll
            for (int c = 0; c < Cdim; c++) p += s_am[k][c] * s_am[l][c];
            p = fminf(fmaxf(p, 1e-4f), 1.f - 1e-4f);
            const float lp = logf(p);
            cl += (d >= 0.5f) ? -lp : lp;
        }
    }
    float whl = (t < Sdim) ? s_whs[t] : 0.f;
    #pragma unroll
    for (int off = 32; off > 0; off >>= 1) {
        cl  += __shfl_down(cl,  off);
        ds  += __shfl_down(ds,  off);
        whl += __shfl_down(whl, off);
    }
    if (t == 0) {
        atomicAdd(&out[OUT_SCALARS + 0], cl  * (1.f / (float)NB));
        atomicAdd(&out[OUT_SCALARS + 1], ds  * (1.f / ((float)NB * Kdim * Kdim)));
        atomicAdd(&out[OUT_SCALARS + 2], whl * (1.f / ((float)NB * Sdim)));
    }
}

extern "C" void kernel_launch(void* const* d_in, const int* in_sizes, int n_in,
                              void* d_out, int out_size, void* d_ws, size_t ws_size,
                              hipStream_t stream) {
    (void)in_sizes; (void)n_in; (void)out_size;
    // 0=fushed_features(unused), 1=input_data, 2=w_W, 3=w_b, 4=a1_W, 5=a1_b,
    // 6=a2_W, 7=a2_b, 8=adj_mx_topk_index
    const float* input_data = (const float*)d_in[1];
    const float* w_W  = (const float*)d_in[2];
    const float* w_b  = (const float*)d_in[3];
    const float* a1_W = (const float*)d_in[4];
    const float* a1_b = (const float*)d_in[5];
    const float* a2_W = (const float*)d_in[6];
    const float* a2_b = (const float*)d_in[7];
    const int*   topk = (const int*)d_in[8];
    float* out = (float*)d_out;
    float* ws  = (float*)d_ws;

    if (ws_size >= (size_t)WS_BASE_FLOATS * sizeof(float)) {
        hipLaunchKernelGGL(node_kernel, dim3(NODE_BLOCKS), dim3(256), 0, stream,
                           input_data, w_W, w_b, a1_W, a1_b, ws, out);
        hipLaunchKernelGGL(mega_kernel, dim3(BN_BLOCKS), dim3(256), 0, stream,
                           topk, a2_W, a2_b, ws, out);
    } else {
        hipLaunchKernelGGL(zero_scalars, dim3(1), dim3(64), 0, stream, out);
        hipLaunchKernelGGL(fused_kernel, dim3(NB), dim3(64), 0, stream,
                           input_data, w_W, w_b, a1_W, a1_b, a2_W, a2_b, topk, out);
    }
}

// Round 3
// 103.956 us; speedup vs baseline: 1.5264x; 1.5264x over previous
//
#include <hip/hip_runtime.h>
#include <math.h>

// Problem constants (from reference)
#define Bdim 32
#define Ndim 325
#define Kdim 20
#define Sdim 12      // S_IN == S_OUT == 12
#define Cdim 10
#define Hdim 48      // 4*S_OUT
#define NB   (Bdim*Ndim)                  // 10400 (b,n) pairs
#define OUT_SCALARS (NB*Cdim*Sdim)        // output_data floats, then 3 scalars
#define BN_BLOCKS (NB/4)                  // 2600 blocks (4 bn each)
#define NODE_BLOCKS 260                   // 40 nodes per block
#define NPB 40

// Workspace layout (float offsets); all blocks 16B-aligned.
#define O_WH  0                           // NB*12 node features wh
#define O_HX  (O_WH + NB*Sdim)            // NB*48: hx + a1_b (bias pre-folded)
#define O_HY  (O_HX + NB*Hdim)            // NB*48: hy
#define O_PCL (O_HY + NB*Hdim)            // BN_BLOCKS cluster-loss partials
#define O_PDS (O_PCL + BN_BLOCKS)         // BN_BLOCKS dist-sum partials
#define O_PWH (O_PDS + BN_BLOCKS)         // NODE_BLOCKS wh-sum partials
#define WS_BASE_FLOATS (O_PWH + NODE_BLOCKS)

__device__ __forceinline__ float leaky(float x) { return x >= 0.f ? x : 0.5f * x; }

// ---------------------------------------------------------------------------
// K1: node kernel (verified 256-thread layout). 260 blocks; 40 nodes each.
// wh -> LDS + ws; hx(+b1), hy -> ws; per-BLOCK wh-sum partial.
// ---------------------------------------------------------------------------
__global__ __launch_bounds__(256)
void node_kernel(const float* __restrict__ x,
                 const float* __restrict__ wW, const float* __restrict__ wb,
                 const float* __restrict__ A1, const float* __restrict__ b1,
                 float* __restrict__ ws)
{
    __shared__ float s_wh[NPB][Sdim];
    __shared__ float s_r[4];
    const int tid = threadIdx.x;
    const int base = blockIdx.x * NPB;

    float v = 0.f;  // wh partial
    // wh: 40*12 = 480 elems
    #pragma unroll
    for (int rep = 0; rep < 2; rep++) {
        const int e = tid + rep * 256;
        if (e < NPB * Sdim) {
            const int n = e / Sdim, s = e - n * Sdim;
            const float* xr = x + (size_t)(base + n) * Sdim;
            float acc = wb[s];
            #pragma unroll
            for (int i = 0; i < Sdim; i++) acc += xr[i] * wW[i * Sdim + s];
            acc = leaky(acc);
            s_wh[n][s] = acc;
            ws[O_WH + (size_t)(base + n) * Sdim + s] = acc;
            v += acc;
        }
    }
    __syncthreads();

    // hx/hy: 40*96 = 3840 elems
    #pragma unroll
    for (int rep = 0; rep < 15; rep++) {
        const int e = tid + rep * 256;
        const int n = e / 96, r = e - n * 96;
        const int which = r / Hdim, d = r - which * Hdim;
        const float4 w0 = *(const float4*)&s_wh[n][0];
        const float4 w1 = *(const float4*)&s_wh[n][4];
        const float4 w2 = *(const float4*)&s_wh[n][8];
        const float* Ac = A1 + (which * Sdim) * Hdim + d;  // stride Hdim over s
        float acc = which ? 0.f : b1[d];                   // fold a1_b into hx
        acc += w0.x*Ac[0*Hdim] + w0.y*Ac[1*Hdim] + w0.z*Ac[2*Hdim] + w0.w*Ac[3*Hdim]
             + w1.x*Ac[4*Hdim] + w1.y*Ac[5*Hdim] + w1.z*Ac[6*Hdim] + w1.w*Ac[7*Hdim]
             + w2.x*Ac[8*Hdim] + w2.y*Ac[9*Hdim] + w2.z*Ac[10*Hdim] + w2.w*Ac[11*Hdim];
        ws[(which ? O_HY : O_HX) + (size_t)(base + n) * Hdim + d] = acc;
    }

    // block-reduce wh partial
    #pragma unroll
    for (int off = 32; off > 0; off >>= 1) v += __shfl_down(v, off);
    if ((tid & 63) == 0) s_r[tid >> 6] = v;
    __syncthreads();
    if (tid == 0) ws[O_PWH + blockIdx.x] = s_r[0] + s_r[1] + s_r[2] + s_r[3];
}

__device__ __forceinline__ float dot12(const float4& a0, const float4& a1, const float4& a2,
                                       const float4& b0, const float4& b1, const float4& b2)
{
    return a0.x*b0.x + a0.y*b0.y + a0.z*b0.z + a0.w*b0.w
         + a1.x*b1.x + a1.y*b1.y + a1.z*b1.z + a1.w*b1.w
         + a2.x*b2.x + a2.y*b2.y + a2.z*b2.z + a2.w*b2.w;
}

// ---------------------------------------------------------------------------
// K2 (merged att+bn): 4 bn per 256-thread block.
// Phase 0: stage A2 (padded rows, stride 12) + the block's 80 topk indices.
// Phase 1: lanes 0..159 = 2 lanes per edge. ALL 12 hx/hy float4 loads are
//          hoisted into registers BEFORE the compute loop (12 concurrent
//          vmem loads -> one latency stall instead of six serial ones; the
//          round-2 profile showed VGPR_Count=44, proving the compiler did
//          not hoist them on its own). Then logits from LDS A2 wide reads,
//          shfl_xor combine, softmax -> s_am. Lanes 160..255 gather whj.
// Phase 2: per-slot norm (t<20) + einsum (20<=t<50); __syncthreads;
//          loss over 2x2 row-tiles spread across all 256 lanes.
// Tail: per-block partial STORES to ws (no atomics -- round-2's same-address
//       atomicAdd tail serialized at the coherent point and doubled K2).
// ---------------------------------------------------------------------------
__global__ __launch_bounds__(256)
void mega_kernel(const int* __restrict__ topk,
                 const float* __restrict__ A2, const float* __restrict__ b2,
                 float* __restrict__ ws, float* __restrict__ out)
{
    __shared__ float s_A2  [Hdim * 12];     // 48 rows, stride 12 (pad 2)
    __shared__ int   s_topk[80];
    __shared__ float s_whj [4][Kdim][12];   // 48B rows, float4-aligned
    __shared__ float s_am  [4][Kdim][12];   // probs, c padded with zeros
    __shared__ float s_invn[4][Kdim];
    __shared__ float s_red[2][4];

    const int tid = threadIdx.x;
    const int slot = tid >> 6, t = tid & 63;

    // ---- phase 0: stage A2 (padded) and topk ----
    if (tid < 120) {
        const int e0 = tid * 4;   // 4 consecutive source floats
        #pragma unroll
        for (int u = 0; u < 4; u++) {
            const int e = e0 + u;
            const int d = e / Cdim, c = e - d * Cdim;
            s_A2[d * 12 + c] = A2[e];
        }
    } else if (tid < 200) {
        s_topk[tid - 120] = topk[blockIdx.x * 80 + (tid - 120)];
    }
    __syncthreads();

    if (tid < 160) {
        // ---- edge pair lanes: e = tid>>1, half = tid&1, 24 d's each ----
        const int e = tid >> 1, half = tid & 1;
        const int gid = blockIdx.x * 80 + e;
        const int bn_e = gid / Kdim;
        const int b_e  = bn_e / Ndim;
        const int j    = s_topk[e];
        const int ek   = e / 20, kk = e - ek * 20;   // (slot, k) of this edge

        const float4* hx4 = (const float4*)(ws + O_HX + (size_t)bn_e * Hdim) + half * 6;
        const float4* hy4 = (const float4*)(ws + O_HY + ((size_t)b_e * Ndim + j) * Hdim) + half * 6;

        // hoist ALL global loads first: 12 outstanding vmem ops
        float4 xv[6], yv[6];
        #pragma unroll
        for (int q = 0; q < 6; q++) xv[q] = hx4[q];
        #pragma unroll
        for (int q = 0; q < 6; q++) yv[q] = hy4[q];

        float acc[Cdim];
        #pragma unroll
        for (int c = 0; c < Cdim; c++) acc[c] = 0.f;
        #pragma unroll
        for (int q = 0; q < 6; q++) {
            const float hh[4] = { leaky(xv[q].x + yv[q].x), leaky(xv[q].y + yv[q].y),
                                  leaky(xv[q].z + yv[q].z), leaky(xv[q].w + yv[q].w) };
            #pragma unroll
            for (int i = 0; i < 4; i++) {
                const int d = half * 24 + q * 4 + i;
                const float* Ar = &s_A2[d * 12];
                const float4 r0 = *(const float4*)(Ar + 0);
                const float4 r1 = *(const float4*)(Ar + 4);
                const float2 r2 = *(const float2*)(Ar + 8);
                const float h = hh[i];
                acc[0] += h * r0.x; acc[1] += h * r0.y;
                acc[2] += h * r0.z; acc[3] += h * r0.w;
                acc[4] += h * r1.x; acc[5] += h * r1.y;
                acc[6] += h * r1.z; acc[7] += h * r1.w;
                acc[8] += h * r2.x; acc[9] += h * r2.y;
            }
        }
        float full[Cdim];
        #pragma unroll
        for (int c = 0; c < Cdim; c++) full[c] = acc[c] + __shfl_xor(acc[c], 1);
        if (half == 0) {
            float m = -1e30f;
            #pragma unroll
            for (int c = 0; c < Cdim; c++) { full[c] = leaky(full[c] + b2[c]); m = fmaxf(m, full[c]); }
            float sum = 0.f;
            #pragma unroll
            for (int c = 0; c < Cdim; c++) { full[c] = __expf(full[c] - m); sum += full[c]; }
            const float inv = 1.f / sum;
            *(float4*)&s_am[ek][kk][0] = make_float4(full[0]*inv, full[1]*inv, full[2]*inv, full[3]*inv);
            *(float4*)&s_am[ek][kk][4] = make_float4(full[4]*inv, full[5]*inv, full[6]*inv, full[7]*inv);
            *(float4*)&s_am[ek][kk][8] = make_float4(full[8]*inv, full[9]*inv, 0.f, 0.f);
        }
    } else {
        // ---- gather lanes (96): 240 float4s of whj ----
        for (int i = tid - 160; i < 240; i += 96) {
            const int kf = i / 3, q = i - kf * 3;          // kf in [0,80)
            const int sl = kf / 20, k = kf - sl * 20;
            const int bn_i = (blockIdx.x * 80 + kf) / Kdim;
            const int b_i  = bn_i / Ndim;
            const int j    = s_topk[kf];
            const float4 v = *(const float4*)(ws + O_WH + ((size_t)b_i * Ndim + j) * Sdim + q * 4);
            *(float4*)&s_whj[sl][k][q * 4] = v;
        }
    }
    __syncthreads();

    const int bn = blockIdx.x * 4 + slot;
    float cl = 0.f, ds = 0.f;

    if (t < Kdim) {
        // per-k norm factor + diagonal dist contribution
        const float4 w0 = *(const float4*)&s_whj[slot][t][0];
        const float4 w1 = *(const float4*)&s_whj[slot][t][4];
        const float4 w2 = *(const float4*)&s_whj[slot][t][8];
        const float nn = dot12(w0, w1, w2, w0, w1, w2);
        const float invn = 1.f / (sqrtf(nn) + 1e-8f);
        s_invn[slot][t] = invn;
        ds += nn * invn * invn;               // dist_mat diagonal term
    } else if (t < Kdim + 30) {
        // output einsum: lane = (c, s-quad), float4 stores
        const int e = t - Kdim, c = e / 3, sq = e - c * 3;
        float4 o = make_float4(0.f, 0.f, 0.f, 0.f);
        #pragma unroll
        for (int k = 0; k < Kdim; k++) {
            const float a = s_am[slot][k][c];
            const float4 w = *(const float4*)&s_whj[slot][k][sq * 4];
            o.x += a * w.x; o.y += a * w.y; o.z += a * w.z; o.w += a * w.w;
        }
        *(float4*)(out + (size_t)bn * (Cdim * Sdim) + c * Sdim + sq * 4) = o;
    }
    __syncthreads();   // s_invn (cross-slot) must be visible to loss lanes

    // ---- loss: 2x2 row-tiles, 55 tiles/slot * 4 slots = 220 tasks ----
    if (tid < 220) {
        const int slot_l = tid / 55;
        const int t55 = tid - slot_l * 55;
        const int gi = (int)((21.0f - sqrtf((float)(441 - 8 * t55))) * 0.5f);
        const int gj = gi + (t55 - (gi * (21 - gi)) / 2);
        const int i0 = 2 * gi, j0 = 2 * gj;
        const bool diag = (gi == gj);

        const float4* W = (const float4*)&s_whj[slot_l][0][0];
        const float4* P = (const float4*)&s_am [slot_l][0][0];

        float4 wi[2][3], wj[2][3], pi[2][3], pj[2][3];
        #pragma unroll
        for (int u = 0; u < 2; u++) {
            #pragma unroll
            for (int q = 0; q < 3; q++) {
                wi[u][q] = W[(i0 + u) * 3 + q];
                wj[u][q] = W[(j0 + u) * 3 + q];
                pi[u][q] = P[(i0 + u) * 3 + q];
                pj[u][q] = P[(j0 + u) * 3 + q];
            }
        }
        const float inv_i[2] = { s_invn[slot_l][i0], s_invn[slot_l][i0 + 1] };
        const float inv_j[2] = { s_invn[slot_l][j0], s_invn[slot_l][j0 + 1] };

        #pragma unroll
        for (int ii = 0; ii < 2; ii++) {
            #pragma unroll
            for (int jj = 0; jj < 2; jj++) {
                const float wgt = diag ? ((ii == 0 && jj == 1) ? 2.f : 0.f) : 2.f;
                const float draw = dot12(wi[ii][0], wi[ii][1], wi[ii][2],
                                         wj[jj][0], wj[jj][1], wj[jj][2]);
                const float d = draw * inv_i[ii] * inv_j[jj];
                float p = dot12(pi[ii][0], pi[ii][1], pi[ii][2],
                                pj[jj][0], pj[jj][1], pj[jj][2]);   // pads are 0
                p = fminf(fmaxf(p, 1e-4f), 1.f - 1e-4f);
                const float lp = __logf(p);
                ds += wgt * d;
                cl += wgt * ((d >= 0.5f) ? -lp : lp);
            }
        }
    }

    // block-wide reduce -> per-block partial stores (NO atomics)
    #pragma unroll
    for (int off = 32; off > 0; off >>= 1) {
        cl += __shfl_down(cl, off);
        ds += __shfl_down(ds, off);
    }
    if (t == 0) { s_red[0][slot] = cl; s_red[1][slot] = ds; }
    __syncthreads();
    if (tid == 0) {
        ws[O_PCL + blockIdx.x] = s_red[0][0] + s_red[0][1] + s_red[0][2] + s_red[0][3];
        ws[O_PDS + blockIdx.x] = s_red[1][0] + s_red[1][1] + s_red[1][2] + s_red[1][3];
    }
}

// ---------------------------------------------------------------------------
// K3: reduce partials -> 3 output scalars (tiny)
// ---------------------------------------------------------------------------
__global__ __launch_bounds__(1024)
void finalize(const float* __restrict__ ws, float* __restrict__ out)
{
    const int t = threadIdx.x;
    float cl = 0.f, ds = 0.f, wm = 0.f;
    for (int i = t; i < BN_BLOCKS; i += 1024) {
        cl += ws[O_PCL + i]; ds += ws[O_PDS + i];
    }
    if (t < NODE_BLOCKS) wm = ws[O_PWH + t];
    #pragma unroll
    for (int off = 32; off > 0; off >>= 1) {
        cl += __shfl_down(cl, off);
        ds += __shfl_down(ds, off);
        wm += __shfl_down(wm, off);
    }
    __shared__ float r[3][16];
    const int w = t >> 6, lane = t & 63;
    if (lane == 0) { r[0][w] = cl; r[1][w] = ds; r[2][w] = wm; }
    __syncthreads();
    if (t == 0) {
        float c = 0.f, d = 0.f, m = 0.f;
        #pragma unroll
        for (int i = 0; i < 16; i++) { c += r[0][i]; d += r[1][i]; m += r[2][i]; }
        out[OUT_SCALARS + 0] = c * (1.f / (float)NB);
        out[OUT_SCALARS + 1] = d * (1.f / ((float)NB * Kdim * Kdim));
        out[OUT_SCALARS + 2] = m * (1.f / ((float)NB * Sdim));
    }
}

// ---------------------------------------------------------------------------
// Fallback: round-1 monolithic kernel (used only if ws is too small)
// ---------------------------------------------------------------------------
__global__ void zero_scalars(float* out) {
    const int t = threadIdx.x;
    if (t < 3) out[OUT_SCALARS + t] = 0.f;
}

__global__ __launch_bounds__(64)
void fused_kernel(const float* __restrict__ input_data,
                  const float* __restrict__ w_W,  const float* __restrict__ w_b,
                  const float* __restrict__ a1_W, const float* __restrict__ a1_b,
                  const float* __restrict__ a2_W, const float* __restrict__ a2_b,
                  const int*   __restrict__ topk,
                  float* __restrict__ out)
{
    __shared__ float s_wW[Sdim * Sdim];
    __shared__ float s_wb[Sdim];
    __shared__ float s_A1[2 * Sdim * Hdim];
    __shared__ float s_b1[Hdim];
    __shared__ float s_A2f[Hdim * Cdim];
    __shared__ float s_b2f[Cdim];
    __shared__ float s_whs[Sdim];
    __shared__ float s_hx[Hdim];
    __shared__ float s_whj[Kdim][Sdim + 1];
    __shared__ float s_hid[Kdim][Hdim + 1];
    __shared__ float s_am [Kdim][Cdim + 1];
    __shared__ float s_wtn[Kdim][Sdim + 1];
    __shared__ int   s_idx[Kdim];

    const int t = threadIdx.x, bn = blockIdx.x, b = bn / Ndim;

    for (int i = t; i < Sdim * Sdim; i += 64)      s_wW[i] = w_W[i];
    if (t < Sdim)                                  s_wb[t] = w_b[t];
    for (int i = t; i < 2 * Sdim * Hdim; i += 64)  s_A1[i] = a1_W[i];
    if (t < Hdim)                                  s_b1[t] = a1_b[t];
    for (int i = t; i < Hdim * Cdim; i += 64)      s_A2f[i] = a2_W[i];
    if (t < Cdim)                                  s_b2f[t] = a2_b[t];
    if (t < Kdim)                                  s_idx[t] = topk[(size_t)bn * Kdim + t];
    __syncthreads();

    const float* xs = input_data + (size_t)bn * Sdim;
    if (t < Sdim) {
        float acc = s_wb[t];
        #pragma unroll
        for (int i = 0; i < Sdim; i++) acc += xs[i] * s_wW[i * Sdim + t];
        s_whs[t] = leaky(acc);
    }
    __syncthreads();

    if (t < Hdim) {
        float acc = 0.f;
        #pragma unroll
        for (int s = 0; s < Sdim; s++) acc += s_whs[s] * s_A1[s * Hdim + t];
        s_hx[t] = acc;
    }
    for (int e = t; e < Kdim * Sdim; e += 64) {
        const int k = e / Sdim, ss = e - k * Sdim;
        const float* xj = input_data + ((size_t)b * Ndim + s_idx[k]) * Sdim;
        float acc = s_wb[ss];
        #pragma unroll
        for (int i = 0; i < Sdim; i++) acc += xj[i] * s_wW[i * Sdim + ss];
        s_whj[k][ss] = leaky(acc);
    }
    __syncthreads();

    for (int e = t; e < Kdim * Hdim; e += 64) {
        const int k = e / Hdim, d = e - k * Hdim;
        float acc = s_hx[d] + s_b1[d];
        #pragma unroll
        for (int s = 0; s < Sdim; s++) acc += s_whj[k][s] * s_A1[(Sdim + s) * Hdim + d];
        s_hid[k][d] = leaky(acc);
    }
    __syncthreads();

    for (int e = t; e < Kdim * Cdim; e += 64) {
        const int k = e / Cdim, c = e - k * Cdim;
        float acc = s_b2f[c];
        #pragma unroll
        for (int d = 0; d < Hdim; d++) acc += s_hid[k][d] * s_A2f[d * Cdim + c];
        s_am[k][c] = leaky(acc);
    }
    __syncthreads();

    if (t < Kdim) {
        float m = -1e30f;
        #pragma unroll
        for (int c = 0; c < Cdim; c++) m = fmaxf(m, s_am[t][c]);
        float ex[Cdim]; float sum = 0.f;
        #pragma unroll
        for (int c = 0; c < Cdim; c++) { ex[c] = expf(s_am[t][c] - m); sum += ex[c]; }
        const float inv = 1.f / sum;
        #pragma unroll
        for (int c = 0; c < Cdim; c++) s_am[t][c] = ex[c] * inv;
        float nn = 0.f;
        #pragma unroll
        for (int s = 0; s < Sdim; s++) nn += s_whj[t][s] * s_whj[t][s];
        const float invn = 1.f / (sqrtf(nn) + 1e-8f);
        #pragma unroll
        for (int s = 0; s < Sdim; s++) s_wtn[t][s] = s_whj[t][s] * invn;
    }
    __syncthreads();

    float* op = out + (size_t)bn * (Cdim * Sdim);
    for (int e = t; e < Cdim * Sdim; e += 64) {
        const int c = e / Sdim, ss = e - c * Sdim;
        float acc = 0.f;
        #pragma unroll
        for (int k = 0; k < Kdim; k++) acc += s_am[k][c] * s_whj[k][ss];
        op[e] = acc;
    }

    float cl = 0.f, ds = 0.f;
    for (int e = t; e < Kdim * Kdim; e += 64) {
        const int k = e / Kdim, l = e - k * Kdim;
        float d = 0.f;
        #pragma unroll
        for (int s = 0; s < Sdim; s++) d += s_wtn[k][s] * s_wtn[l][s];
        ds += d;
        if (k != l) {
            float p = 0.f;
            #pragma unroll
            for (int c = 0; c < Cdim; c++) p += s_am[k][c] * s_am[l][c];
            p = fminf(fmaxf(p, 1e-4f), 1.f - 1e-4f);
            const float lp = logf(p);
            cl += (d >= 0.5f) ? -lp : lp;
        }
    }
    float whl = (t < Sdim) ? s_whs[t] : 0.f;
    #pragma unroll
    for (int off = 32; off > 0; off >>= 1) {
        cl  += __shfl_down(cl,  off);
        ds  += __shfl_down(ds,  off);
        whl += __shfl_down(whl, off);
    }
    if (t == 0) {
        atomicAdd(&out[OUT_SCALARS + 0], cl  * (1.f / (float)NB));
        atomicAdd(&out[OUT_SCALARS + 1], ds  * (1.f / ((float)NB * Kdim * Kdim)));
        atomicAdd(&out[OUT_SCALARS + 2], whl * (1.f / ((float)NB * Sdim)));
    }
}

extern "C" void kernel_launch(void* const* d_in, const int* in_sizes, int n_in,
                              void* d_out, int out_size, void* d_ws, size_t ws_size,
                              hipStream_t stream) {
    (void)in_sizes; (void)n_in; (void)out_size;
    // 0=fushed_features(unused), 1=input_data, 2=w_W, 3=w_b, 4=a1_W, 5=a1_b,
    // 6=a2_W, 7=a2_b, 8=adj_mx_topk_index
    const float* input_data = (const float*)d_in[1];
    const float* w_W  = (const float*)d_in[2];
    const float* w_b  = (const float*)d_in[3];
    const float* a1_W = (const float*)d_in[4];
    const float* a1_b = (const float*)d_in[5];
    const float* a2_W = (const float*)d_in[6];
    const float* a2_b = (const float*)d_in[7];
    const int*   topk = (const int*)d_in[8];
    float* out = (float*)d_out;
    float* ws  = (float*)d_ws;

    if (ws_size >= (size_t)WS_BASE_FLOATS * sizeof(float)) {
        hipLaunchKernelGGL(node_kernel, dim3(NODE_BLOCKS), dim3(256), 0, stream,
                           input_data, w_W, w_b, a1_W, a1_b, ws);
        hipLaunchKernelGGL(mega_kernel, dim3(BN_BLOCKS), dim3(256), 0, stream,
                           topk, a2_W, a2_b, ws, out);
        hipLaunchKernelGGL(finalize, dim3(1), dim3(1024), 0, stream, ws, out);
    } else {
        hipLaunchKernelGGL(zero_scalars, dim3(1), dim3(64), 0, stream, out);
        hipLaunchKernelGGL(fused_kernel, dim3(NB), dim3(64), 0, stream,
                           input_data, w_W, w_b, a1_W, a1_b, a2_W, a2_b, topk, out);
    }
}